// Round 6
// baseline (226.336 us; speedup 1.0000x reference)
//
#include <hip/hip_runtime.h>
#include <hip/hip_bf16.h>

#define N_NODES 100000
#define N_EDGES 1000000
#define EMB 64
#define HID 64
#define VOCAB 128
#define N_GRAPHS 2048

#define CBUCKET 256                                    // nodes per bucket
#define NBK ((N_NODES + CBUCKET - 1) / CBUCKET)        // 391
#define CAP 4096                                       // slots per bucket (E[cnt]=2560, 30 sigma)
#define CHUNK 4096
#define SCAT_BLOCKS ((N_EDGES + CHUNK - 1) / CHUNK)    // 245
#define GB ((N_NODES + 255) / 256)                     // 391 gstart blocks

#define BCASTF(v, l) __int_as_float(__builtin_amdgcn_readlane(__float_as_int(v), (l)))

typedef __attribute__((ext_vector_type(8))) short short8;
typedef __attribute__((ext_vector_type(4))) float f32x4;
typedef __attribute__((ext_vector_type(2))) float f32x2;

__device__ __forceinline__ float bf2f(unsigned short u) {
    return __uint_as_float((unsigned)u << 16);
}
__device__ __forceinline__ unsigned short f2bf(float f) {
    return __bfloat16_as_ushort(__float2bfloat16(f));
}

// ---- merged scatter + setup: blocks [0,245) scatter, [245,636) gstart,
//      [636,668) precompute. cursor/gsum pre-zeroed by one memset.
__global__ __launch_bounds__(256) void scatter_kernel(
    const int* __restrict__ src, const int* __restrict__ dst,
    const int* __restrict__ x,
    int* __restrict__ cursor, unsigned* __restrict__ edge8,
    const int* __restrict__ batch, int* __restrict__ gstart,
    const float* __restrict__ emb, const float* __restrict__ W1l,
    const float* __restrict__ W1r,
    const float* __restrict__ W2l, const float* __restrict__ W2r,
    float* __restrict__ embW1l, float* __restrict__ embW1r,
    unsigned short* __restrict__ w2frag, unsigned char* __restrict__ p8z)
{
    __shared__ unsigned earr[CHUNK];            // 16 KB packed payload
    __shared__ unsigned short karr[CHUNK];      // 8 KB bucket key (0..390)
    __shared__ int bcnt[NBK];
    __shared__ int bbase[NBK];
    int b = blockIdx.x;
    int t = threadIdx.x;

    if (b < SCAT_BLOCKS) {
        // ---- scatter: LDS-staged chunk, per-(block,bucket) run reservation
        // 32-bit payload: src(17) | x[src](7, bits 17..23) | local_dst(8, bits 24..31)
        for (int i = t; i < NBK; i += 256) bcnt[i] = 0;
        __syncthreads();
        int e0 = b * CHUNK;
        int n = min(e0 + CHUNK, N_EDGES) - e0;
        for (int i = t; i < n; i += 256) {
            int d = dst[e0 + i];
            int s = src[e0 + i];
            int xv = x[s];                      // random 4B read, 400KB L2-hot
            int k = d >> 8;
            earr[i] = (unsigned)s | ((unsigned)xv << 17) | ((unsigned)(d & 255) << 24);
            karr[i] = (unsigned short)k;
            atomicAdd(&bcnt[k], 1);
        }
        __syncthreads();
        for (int i = t; i < NBK; i += 256) {
            int c = bcnt[i];
            bbase[i] = i * CAP + (c ? atomicAdd(&cursor[i], c) : 0);
            bcnt[i] = 0;                        // reuse as local cursor
        }
        __syncthreads();
        for (int i = t; i < n; i += 256) {
            int k = karr[i];
            int off = atomicAdd(&bcnt[k], 1);
            edge8[bbase[k] + off] = earr[i];    // dense single-writer runs
        }
    } else if (b < SCAT_BLOCKS + GB) {
        // ---- graph boundaries (batch sorted)
        int i = (b - SCAT_BLOCKS) * 256 + t;
        if (i >= N_NODES) return;
        int bg = batch[i];
        int bp = (i == 0) ? -1 : batch[i - 1];
        for (int g = bp + 1; g <= bg; ++g) gstart[g] = i;
        if (i == N_NODES - 1)
            for (int g = bg + 1; g <= N_GRAPHS; ++g) gstart[g] = N_NODES;
    } else {
        // ---- precompute embW1l/embW1r + pack W2 B-fragments
        int vb = b - SCAT_BLOCKS - GB;
        // zero-row for sage2's branch-free gather (fp8 0x00 == +0.0)
        if (vb == 0 && t < 16)
            ((unsigned*)(p8z + (size_t)N_NODES * 64))[t] = 0u;
        int wave = t >> 6, lane = t & 63;
        int v = vb * 4 + wave;
        if (v < VOCAB) {
            float er = emb[v * 64 + lane];       // lane = d
            float al = 0.f, ar = 0.f;
#pragma unroll 8
            for (int d = 0; d < 64; ++d) {
                float e = BCASTF(er, d);
                al += e * W1l[d * 64 + lane];
                ar += e * W1r[d * 64 + lane];
            }
            embW1l[v * 64 + lane] = al;
            embW1r[v * 64 + lane] = ar;
        }
        // W2 B-fragment packing: g = tt*1024 + h*512 + l*8 + j
        int g = vb * 256 + t;
        int j = g & 7, l = (g >> 3) & 63, h = (g >> 9) & 1, tt = g >> 10;
        int k = h * 32 + ((l >> 4) * 8) + j;
        int n = tt * 16 + (l & 15);
        float w = (n < 64) ? W2l[k * 64 + n] : W2r[k * 64 + (n - 64)];
        w2frag[g] = f2bf(w);
    }
}

// ---- per-bucket CSR build (rowstart/deg/col), dense writes ------
// col entry = src (17b) | x[src] (7b). Blocks 0..7 pack W1 B-fragments.
__global__ __launch_bounds__(256) void csr_kernel(
    const unsigned* __restrict__ edge8, const int* __restrict__ cursor,
    int* __restrict__ row_start, int* __restrict__ deg, int* __restrict__ col,
    const float* __restrict__ embW1l, const float* __restrict__ embW1r,
    unsigned short* __restrict__ w1frag)
{
    __shared__ int cnt[CBUCKET];
    __shared__ int scn[CBUCKET];
    int b = blockIdx.x;                   // NBK blocks
    int t = threadIdx.x;

    if (b < 8) {
        // w1frag[( (kf*4+nt)*64 + l)*8 + j] = bf16 of B[k][n],
        //   k = kf*32 + (l>>4)*8 + j, n = nt*16 + (l&15); k>=128 -> embW1r
        int g0 = (b * 256 + t) * 8;
#pragma unroll
        for (int j = 0; j < 8; ++j) {
            int g = g0 + j;
            int fi = g >> 9;
            int kf = fi >> 2, nt = fi & 3;
            int l = (g >> 3) & 63, jj = g & 7;
            int kg = kf * 32 + ((l >> 4) << 3) + jj;
            int n = nt * 16 + (l & 15);
            float w = (kg < 128) ? embW1l[kg * 64 + n] : embW1r[(kg - 128) * 64 + n];
            w1frag[g] = f2bf(w);
        }
    }

    int lo = b * CAP, hi = lo + cursor[b];  // cursor holds final fill count
    cnt[t] = 0;
    __syncthreads();
    for (int i = lo + t; i < hi; i += 256)
        atomicAdd(&cnt[edge8[i] >> 24], 1);
    __syncthreads();
    int v = cnt[t];
    scn[t] = v;
    __syncthreads();
    for (int off = 1; off < 256; off <<= 1) {
        int tmp = (t >= off) ? scn[t - off] : 0;
        __syncthreads();
        scn[t] += tmp;
        __syncthreads();
    }
    int excl = scn[t] - v;
    int node = b * CBUCKET + t;
    if (node < N_NODES) { row_start[node] = lo + excl; deg[node] = v; }
    cnt[t] = excl;                        // reuse as cursor
    __syncthreads();
    for (int i = lo + t; i < hi; i += 256) {
        unsigned e = edge8[i];
        int slot = atomicAdd(&cnt[e >> 24], 1);
        col[lo + slot] = (int)(e & 0xFFFFFF);   // src | x<<17 (24 bits)
    }
}

// ---- col16: padded first-16 neighbor indices per node (ZROW pad) --------
// 16 threads/node, direct strided reads from the dense CSR runs.
#define ZROW N_NODES
__global__ __launch_bounds__(256) void col16_kernel(
    const int* __restrict__ row_start, const int* __restrict__ deg,
    const int* __restrict__ col, int* __restrict__ col16)
{
    int node = blockIdx.x * 16 + (threadIdx.x >> 4);    // 16 nodes/block
    int j = threadIdx.x & 15;
    if (node >= N_NODES) return;
    int d = deg[node];
    col16[node * 16 + j] = (j < d) ? (col[row_start[node] + j] & 0x1FFFF) : ZROW;
}

// ---- sage1, histogram-MFMA form (round-4 proven, unchanged) -------------
__global__ __launch_bounds__(256) void sage1_kernel(
    const int* __restrict__ x, const int* __restrict__ deg,
    const unsigned* __restrict__ edge8, const int* __restrict__ cursor,
    const unsigned short* __restrict__ w1frag,
    const unsigned short* __restrict__ w2frag, const float* __restrict__ b1,
    unsigned char* __restrict__ p8, unsigned short* __restrict__ q16)
{
    __shared__ unsigned hist[128 * 32];         // 16 KB u8[128][128], swizzled words
    __shared__ unsigned short msbuf[128 * 72];  // 18 KB h1 bf16, stride 72
    __shared__ int xl[128];
    __shared__ float invd[128];

    int blk = blockIdx.x, bucket = blk >> 1, half = blk & 1;
    int t = threadIdx.x;
    int nbase = bucket * CBUCKET + half * 128;

    for (int i = t * 4; i < 128 * 32; i += 1024)
        *(uint4*)&hist[i] = (uint4){0u, 0u, 0u, 0u};
    if (t < 128) {
        int node = nbase + t;
        int dv = (node < N_NODES) ? deg[node] : 0;
        invd[t] = 1.0f / fmaxf((float)dv, 1.0f);
        xl[t] = (node < N_NODES) ? x[node] : 0;
    }
    __syncthreads();

    int lo = bucket * CAP, ecnt = cursor[bucket];
    for (int i = t; i < ecnt; i += 256) {
        unsigned e = edge8[lo + i];
        int ld = (int)(e >> 24);
        if ((ld >> 7) == half) {
            int r = ld & 127;
            int xv = (int)((e >> 17) & 127);
            int wc = (xv >> 2) ^ ((r & 7) << 2);        // word swizzle
            atomicAdd(&hist[r * 32 + wc], 1u << ((xv & 3) * 8));
        }
    }
    __syncthreads();

    int wave = t >> 6, lane = t & 63;
    int m = lane & 15;                  // A row / C col index
    int qd = lane >> 4;                 // k-subchunk / C row-group
    int hswz = (m & 7) << 2;            // row m's word swizzle

#pragma unroll
    for (int rt = wave * 2; rt < wave * 2 + 2; ++rt) {
        short8 acnt[4], aself[4];
#pragma unroll
        for (int kf = 0; kf < 4; ++kf) {
            int w0 = (kf * 8 + qd * 2) ^ hswz;
            uint2 u = *(const uint2*)&hist[(rt * 16 + m) * 32 + w0];
            short8 f;
            f[0] = (short)f2bf((float)(u.x & 255));
            f[1] = (short)f2bf((float)((u.x >> 8) & 255));
            f[2] = (short)f2bf((float)((u.x >> 16) & 255));
            f[3] = (short)f2bf((float)(u.x >> 24));
            f[4] = (short)f2bf((float)(u.y & 255));
            f[5] = (short)f2bf((float)((u.y >> 8) & 255));
            f[6] = (short)f2bf((float)((u.y >> 16) & 255));
            f[7] = (short)f2bf((float)(u.y >> 24));
            acnt[kf] = f;
        }
        int xv = xl[rt * 16 + m];
#pragma unroll
        for (int kf = 0; kf < 4; ++kf) {
            int v = xv - kf * 32 - qd * 8;
            short8 f;
#pragma unroll
            for (int j = 0; j < 8; ++j)
                f[j] = (v == j) ? (short)0x3F80 : (short)0;
            aself[kf] = f;
        }
        float iv0 = invd[rt * 16 + qd * 4 + 0];
        float iv1 = invd[rt * 16 + qd * 4 + 1];
        float iv2 = invd[rt * 16 + qd * 4 + 2];
        float iv3 = invd[rt * 16 + qd * 4 + 3];

#pragma unroll
        for (int nt = 0; nt < 4; ++nt) {
            f32x4 accA = {0.f, 0.f, 0.f, 0.f};
            f32x4 accS = {0.f, 0.f, 0.f, 0.f};
#pragma unroll
            for (int kf = 0; kf < 4; ++kf) {
                short8 bA = *(const short8*)(w1frag + ((kf * 4 + nt) * 64 + lane) * 8);
                accA = __builtin_amdgcn_mfma_f32_16x16x32_bf16(acnt[kf], bA, accA, 0, 0, 0);
            }
#pragma unroll
            for (int kf = 0; kf < 4; ++kf) {
                short8 bS = *(const short8*)(w1frag + (((kf + 4) * 4 + nt) * 64 + lane) * 8);
                accS = __builtin_amdgcn_mfma_f32_16x16x32_bf16(aself[kf], bS, accS, 0, 0, 0);
            }
            int c = nt * 16 + m;
            float b1c = b1[c];
            int rb = rt * 16 + qd * 4;
            msbuf[(rb + 0) * 72 + c] = f2bf(fmaxf(accA[0] * iv0 + accS[0] + b1c, 0.f));
            msbuf[(rb + 1) * 72 + c] = f2bf(fmaxf(accA[1] * iv1 + accS[1] + b1c, 0.f));
            msbuf[(rb + 2) * 72 + c] = f2bf(fmaxf(accA[2] * iv2 + accS[2] + b1c, 0.f));
            msbuf[(rb + 3) * 72 + c] = f2bf(fmaxf(accA[3] * iv3 + accS[3] + b1c, 0.f));
        }
    }
    __syncthreads();

#pragma unroll
    for (int rt = wave * 2; rt < wave * 2 + 2; ++rt) {
        const unsigned short* arow = &msbuf[(rt * 16 + m) * 72 + qd * 8];
        short8 a0 = *(const short8*)(arow);
        short8 a1 = *(const short8*)(arow + 32);
        int rowb = nbase + rt * 16 + qd * 4;

#pragma unroll
        for (int tt = 0; tt < 8; ++tt) {
            short8 b0 = *(const short8*)(w2frag + tt * 1024 + lane * 8);
            short8 b1v = *(const short8*)(w2frag + tt * 1024 + 512 + lane * 8);
            f32x4 acc = {0.f, 0.f, 0.f, 0.f};
            acc = __builtin_amdgcn_mfma_f32_16x16x32_bf16(a0, b0, acc, 0, 0, 0);
            acc = __builtin_amdgcn_mfma_f32_16x16x32_bf16(a1, b1v, acc, 0, 0, 0);
            int o = tt * 16 + m;
            if (o < 64) {
                int pk01 = __builtin_amdgcn_cvt_pk_fp8_f32(acc[0], acc[1], 0, false);
                int pk23 = __builtin_amdgcn_cvt_pk_fp8_f32(acc[2], acc[3], 0, false);
                if (rowb + 0 < N_NODES) p8[(rowb + 0) * 64 + o] = (unsigned char)(pk01 & 0xff);
                if (rowb + 1 < N_NODES) p8[(rowb + 1) * 64 + o] = (unsigned char)((pk01 >> 8) & 0xff);
                if (rowb + 2 < N_NODES) p8[(rowb + 2) * 64 + o] = (unsigned char)(pk23 & 0xff);
                if (rowb + 3 < N_NODES) p8[(rowb + 3) * 64 + o] = (unsigned char)((pk23 >> 8) & 0xff);
            } else {
                int oc = o & 63;
#pragma unroll
                for (int i = 0; i < 4; ++i)
                    if (rowb + i < N_NODES)
                        q16[(rowb + i) * 64 + oc] = f2bf(acc[i]);
            }
        }
    }
}

// ---- sage2: proven lane layout, addresses from col16 via DIRECT loads ----
#define S2_NPW 8
__global__ __launch_bounds__(256) void sage2_kernel(
    const unsigned char* __restrict__ p, const unsigned short* __restrict__ q,
    const int* __restrict__ row_start, const int* __restrict__ deg,
    const int* __restrict__ col, const int* __restrict__ col16,
    const float* __restrict__ b2,
    const float* __restrict__ Wout, const int* __restrict__ batch,
    float* __restrict__ gsum)
{
    int t = threadIdx.x;
    int wave = t >> 6, lane = t & 63;
    int base_node = (blockIdx.x * 4 + wave) * S2_NPW;   // exact cover
    int c = lane & 15;          // feature quad: features 4c..4c+3
    int g = lane >> 4;          // row group 0..3

    float4 b2v = ((const float4*)b2)[c];
    float4 w01 = ((const float4*)Wout)[c * 2];
    float4 w23 = ((const float4*)Wout)[c * 2 + 1];

    int dgs[S2_NPW];
#pragma unroll
    for (int n = 0; n < S2_NPW; ++n)
        dgs[n] = deg[base_node + n];

    // ---- phase 1: 32 independent idx loads (rows g,4+g,8+g,12+g per node)
    int idx[S2_NPW][4];
#pragma unroll
    for (int n = 0; n < S2_NPW; ++n) {
        const int* cp = col16 + (size_t)(base_node + n) * 16 + g;
        idx[n][0] = cp[0];
        idx[n][1] = cp[4];
        idx[n][2] = cp[8];
        idx[n][3] = cp[12];
    }
    __builtin_amdgcn_sched_barrier(0);

    // ---- phase 2: 32 independent p-gathers + 8 q-rows, all in flight ----
    unsigned vv[S2_NPW][4];
    ushort4 qv[S2_NPW];
#pragma unroll
    for (int n = 0; n < S2_NPW; ++n) {
        vv[n][0] = *(const unsigned*)(p + (size_t)idx[n][0] * 64 + c * 4);
        vv[n][1] = *(const unsigned*)(p + (size_t)idx[n][1] * 64 + c * 4);
        vv[n][2] = *(const unsigned*)(p + (size_t)idx[n][2] * 64 + c * 4);
        vv[n][3] = *(const unsigned*)(p + (size_t)idx[n][3] * 64 + c * 4);
    }
#pragma unroll
    for (int n = 0; n < S2_NPW; ++n)
        qv[n] = *(const ushort4*)(q + (size_t)(base_node + n) * 64 + c * 4);
    __builtin_amdgcn_sched_barrier(0);

#define ACC(a, v) { f32x2 f01_ = __builtin_amdgcn_cvt_pk_f32_fp8((int)(v), false); \
                    f32x2 f23_ = __builtin_amdgcn_cvt_pk_f32_fp8((int)(v), true);  \
                    (a).x += f01_.x; (a).y += f01_.y; (a).z += f23_.x; (a).w += f23_.y; }

#pragma unroll
    for (int n = 0; n < S2_NPW; n += 2) {
        int dgA = dgs[n], dgB = dgs[n + 1];

        float4 aA = {0.f,0.f,0.f,0.f}, aB = {0.f,0.f,0.f,0.f};
        ACC(aA, vv[n][0])     ACC(aA, vv[n][1])     ACC(aA, vv[n][2])     ACC(aA, vv[n][3])
        ACC(aB, vv[n + 1][0]) ACC(aB, vv[n + 1][1]) ACC(aB, vv[n + 1][2]) ACC(aB, vv[n + 1][3])

        // --- deg>16 tail: direct col loads, guarded (rare, ~2.6%) ---
        if (dgA > 16) {
            int rsA = row_start[base_node + n];
            for (int j = 16; j < dgA; j += 8) {
                int r0 = j + g, r1 = j + 4 + g;
                int i0 = (r0 < dgA) ? (col[rsA + r0] & 0x1FFFF) : ZROW;
                int i1 = (r1 < dgA) ? (col[rsA + r1] & 0x1FFFF) : ZROW;
                unsigned v0 = *(const unsigned*)(p + (size_t)i0 * 64 + c * 4);
                unsigned v1 = *(const unsigned*)(p + (size_t)i1 * 64 + c * 4);
                ACC(aA, v0) ACC(aA, v1)
            }
        }
        if (dgB > 16) {
            int rsB = row_start[base_node + n + 1];
            for (int j = 16; j < dgB; j += 8) {
                int r0 = j + g, r1 = j + 4 + g;
                int i0 = (r0 < dgB) ? (col[rsB + r0] & 0x1FFFF) : ZROW;
                int i1 = (r1 < dgB) ? (col[rsB + r1] & 0x1FFFF) : ZROW;
                unsigned v0 = *(const unsigned*)(p + (size_t)i0 * 64 + c * 4);
                unsigned v1 = *(const unsigned*)(p + (size_t)i1 * 64 + c * 4);
                ACC(aB, v0) ACC(aB, v1)
            }
        }

        aA.x += __shfl_xor(aA.x, 16, 64); aA.y += __shfl_xor(aA.y, 16, 64);
        aA.z += __shfl_xor(aA.z, 16, 64); aA.w += __shfl_xor(aA.w, 16, 64);
        aB.x += __shfl_xor(aB.x, 16, 64); aB.y += __shfl_xor(aB.y, 16, 64);
        aB.z += __shfl_xor(aB.z, 16, 64); aB.w += __shfl_xor(aB.w, 16, 64);
        aA.x += __shfl_xor(aA.x, 32, 64); aA.y += __shfl_xor(aA.y, 32, 64);
        aA.z += __shfl_xor(aA.z, 32, 64); aA.w += __shfl_xor(aA.w, 32, 64);
        aB.x += __shfl_xor(aB.x, 32, 64); aB.y += __shfl_xor(aB.y, 32, 64);
        aB.z += __shfl_xor(aB.z, 32, 64); aB.w += __shfl_xor(aB.w, 32, 64);

#pragma unroll
        for (int e = 0; e < 2; ++e) {
            int node = base_node + n + e;
            int dg = (e == 0) ? dgA : dgB;
            float4 a = (e == 0) ? aA : aB;
            ushort4 qvv = qv[n + e];
            float inv = 1.0f / fmaxf((float)dg, 1.0f);
            float h0 = fmaxf(a.x * inv + b2v.x + bf2f(qvv.x), 0.f);
            float h1 = fmaxf(a.y * inv + b2v.y + bf2f(qvv.y), 0.f);
            float h2 = fmaxf(a.z * inv + b2v.z + bf2f(qvv.z), 0.f);
            float h3 = fmaxf(a.w * inv + b2v.w + bf2f(qvv.w), 0.f);

            float p0 = h0 * w01.x + h1 * w01.z + h2 * w23.x + h3 * w23.z;
            float p1 = h0 * w01.y + h1 * w01.w + h2 * w23.y + h3 * w23.w;
            if (g != 0) { p0 = 0.f; p1 = 0.f; }         // groups duplicate
            p0 += __shfl_down(p0, 8, 64);  p1 += __shfl_down(p1, 8, 64);
            p0 += __shfl_down(p0, 4, 64);  p1 += __shfl_down(p1, 4, 64);
            p0 += __shfl_down(p0, 2, 64);  p1 += __shfl_down(p1, 2, 64);
            p0 += __shfl_down(p0, 1, 64);  p1 += __shfl_down(p1, 1, 64);
            if (lane == 0) {
                int grp = batch[node];
                atomicAdd(&gsum[grp * 2 + 0], p0);
                atomicAdd(&gsum[grp * 2 + 1], p1);
            }
        }
    }
#undef ACC
}

// ---------------- finalize: out = gsum/cnt + bout ----------------
__global__ __launch_bounds__(256) void finalize_kernel(
    const float* __restrict__ gsum, const int* __restrict__ gstart,
    const float* __restrict__ bout, float* __restrict__ out)
{
    int g = blockIdx.x * 256 + threadIdx.x;
    if (g >= N_GRAPHS) return;
    int cnt = gstart[g + 1] - gstart[g];
    float inv = 1.0f / fmaxf((float)cnt, 1.0f);
    out[g * 2 + 0] = gsum[g * 2 + 0] * inv + bout[0];
    out[g * 2 + 1] = gsum[g * 2 + 1] * inv + bout[1];
}

extern "C" void kernel_launch(void* const* d_in, const int* in_sizes, int n_in,
                              void* d_out, int out_size, void* d_ws, size_t ws_size,
                              hipStream_t stream) {
    const int*   x    = (const int*)  d_in[0];
    const int*   ei   = (const int*)  d_in[1];
    const int*   batch= (const int*)  d_in[2];
    const float* emb  = (const float*)d_in[3];
    const float* W1l  = (const float*)d_in[4];
    const float* b1   = (const float*)d_in[5];
    const float* W1r  = (const float*)d_in[6];
    const float* W2l  = (const float*)d_in[7];
    const float* b2   = (const float*)d_in[8];
    const float* W2r  = (const float*)d_in[9];
    const float* Wout = (const float*)d_in[10];
    const float* bout = (const float*)d_in[11];
    float* out = (float*)d_out;

    const int* src = ei;
    const int* dst = ei + N_EDGES;

    char* ws = (char*)d_ws;
    size_t off = 0;
    unsigned char*  p8     = (unsigned char*) (ws + off); off += (size_t)N_NODES * 64 + 64; // +64B zero row
    unsigned short* q16    = (unsigned short*)(ws + off); off += (size_t)N_NODES * 64 * 2;  // 12.8 MB
    unsigned short* w2frag = (unsigned short*)(ws + off); off += (size_t)8192 * 2;
    unsigned short* w1frag = (unsigned short*)(ws + off); off += (size_t)16384 * 2;         // 32 KB
    float*    embW1l = (float*)   (ws + off); off += (size_t)VOCAB * 64 * 4;
    float*    embW1r = (float*)   (ws + off); off += (size_t)VOCAB * 64 * 4;
    int*      rowst  = (int*)     (ws + off); off += (size_t)N_NODES * 4;
    int*      deg    = (int*)     (ws + off); off += (size_t)N_NODES * 4;
    int*      col    = (int*)     (ws + off); off += (size_t)(NBK * CAP + 256) * 4;   // 6.4 MB
    int*      col16  = (int*)     (ws + off); off += (size_t)(N_NODES + 16) * 16 * 4; // 6.4 MB
    unsigned* edge8  = (unsigned*)(ws + off); off += (size_t)NBK * CAP * 4;           // 6.4 MB
    int*      gstart = (int*)     (ws + off); off += (size_t)(N_GRAPHS + 1) * 4;
    // contiguous zero region: cursor | gsum (one memset)
    int*      cursor = (int*)     (ws + off); off += (size_t)NBK * 4;
    float*    gsum   = (float*)   (ws + off); off += (size_t)N_GRAPHS * 2 * 4;

    hipMemsetAsync(cursor, 0, (size_t)NBK * 4 + (size_t)N_GRAPHS * 2 * 4, stream);

    scatter_kernel<<<SCAT_BLOCKS + GB + 32, 256, 0, stream>>>(
        src, dst, x, cursor, edge8,
        batch, gstart, emb, W1l, W1r, W2l, W2r, embW1l, embW1r, w2frag, p8);
    csr_kernel<<<NBK, 256, 0, stream>>>(edge8, cursor, rowst, deg, col,
                                        embW1l, embW1r, w1frag);
    col16_kernel<<<(N_NODES + 15) / 16, 256, 0, stream>>>(rowst, deg, col, col16);
    sage1_kernel<<<NBK * 2, 256, 0, stream>>>(
        x, deg, edge8, cursor, w1frag, w2frag, b1, p8, q16);
    sage2_kernel<<<N_NODES / (4 * S2_NPW), 256, 0, stream>>>(
        p8, q16, rowst, deg, col, col16, b2, Wout, batch, gsum);
    finalize_kernel<<<(N_GRAPHS + 255) / 256, 256, 0, stream>>>(gsum, gstart, bout, out);
}

// Round 7
// 199.809 us; speedup vs baseline: 1.1328x; 1.1328x over previous
//
#include <hip/hip_runtime.h>
#include <hip/hip_bf16.h>

#define N_NODES 100000
#define N_EDGES 1000000
#define EMB 64
#define HID 64
#define VOCAB 128
#define N_GRAPHS 2048

#define CBUCKET 256                                    // nodes per bucket
#define NBK ((N_NODES + CBUCKET - 1) / CBUCKET)        // 391
#define CAP 4096                                       // slots per bucket (E[cnt]=2560, 30 sigma)
#define CHUNK 4096
#define SCAT_BLOCKS ((N_EDGES + CHUNK - 1) / CHUNK)    // 245
#define GB ((N_NODES + 255) / 256)                     // 391 gstart blocks
#define ZROW N_NODES                                   // zero-row index in p8

#define BCASTF(v, l) __int_as_float(__builtin_amdgcn_readlane(__float_as_int(v), (l)))

typedef __attribute__((ext_vector_type(8))) short short8;
typedef __attribute__((ext_vector_type(4))) float f32x4;
typedef __attribute__((ext_vector_type(2))) float f32x2;

__device__ __forceinline__ float bf2f(unsigned short u) {
    return __uint_as_float((unsigned)u << 16);
}
__device__ __forceinline__ unsigned short f2bf(float f) {
    return __bfloat16_as_ushort(__float2bfloat16(f));
}

// ---- merged scatter + setup: blocks [0,245) scatter, [245,636) gstart,
//      [636,668) precompute. cursor/gsum pre-zeroed by one memset.
__global__ __launch_bounds__(256) void scatter_kernel(
    const int* __restrict__ src, const int* __restrict__ dst,
    const int* __restrict__ x,
    int* __restrict__ cursor, unsigned* __restrict__ edge8,
    const int* __restrict__ batch, int* __restrict__ gstart,
    const float* __restrict__ emb, const float* __restrict__ W1l,
    const float* __restrict__ W1r,
    const float* __restrict__ W2l, const float* __restrict__ W2r,
    float* __restrict__ embW1l, float* __restrict__ embW1r,
    unsigned short* __restrict__ w2frag, unsigned char* __restrict__ p8z)
{
    __shared__ unsigned earr[CHUNK];            // 16 KB packed payload
    __shared__ unsigned short karr[CHUNK];      // 8 KB bucket key (0..390)
    __shared__ int bcnt[NBK];
    __shared__ int bbase[NBK];
    int b = blockIdx.x;
    int t = threadIdx.x;

    if (b < SCAT_BLOCKS) {
        // ---- scatter: LDS-staged chunk, per-(block,bucket) run reservation
        // 32-bit payload: src(17) | x[src](7, bits 17..23) | local_dst(8, bits 24..31)
        for (int i = t; i < NBK; i += 256) bcnt[i] = 0;
        __syncthreads();
        int e0 = b * CHUNK;
        int n = min(e0 + CHUNK, N_EDGES) - e0;
        for (int i = t; i < n; i += 256) {
            int d = dst[e0 + i];
            int s = src[e0 + i];
            int xv = x[s];                      // random 4B read, 400KB L2-hot
            int k = d >> 8;
            earr[i] = (unsigned)s | ((unsigned)xv << 17) | ((unsigned)(d & 255) << 24);
            karr[i] = (unsigned short)k;
            atomicAdd(&bcnt[k], 1);
        }
        __syncthreads();
        for (int i = t; i < NBK; i += 256) {
            int c = bcnt[i];
            bbase[i] = i * CAP + (c ? atomicAdd(&cursor[i], c) : 0);
            bcnt[i] = 0;                        // reuse as local cursor
        }
        __syncthreads();
        for (int i = t; i < n; i += 256) {
            int k = karr[i];
            int off = atomicAdd(&bcnt[k], 1);
            edge8[bbase[k] + off] = earr[i];    // dense single-writer runs
        }
    } else if (b < SCAT_BLOCKS + GB) {
        // ---- graph boundaries (batch sorted)
        int i = (b - SCAT_BLOCKS) * 256 + t;
        if (i >= N_NODES) return;
        int bg = batch[i];
        int bp = (i == 0) ? -1 : batch[i - 1];
        for (int g = bp + 1; g <= bg; ++g) gstart[g] = i;
        if (i == N_NODES - 1)
            for (int g = bg + 1; g <= N_GRAPHS; ++g) gstart[g] = N_NODES;
    } else {
        // ---- precompute embW1l/embW1r + pack W2 B-fragments
        int vb = b - SCAT_BLOCKS - GB;
        // zero-row for sage2's branch-free gather (fp8 0x00 == +0.0)
        if (vb == 0 && t < 16)
            ((unsigned*)(p8z + (size_t)N_NODES * 64))[t] = 0u;
        int wave = t >> 6, lane = t & 63;
        int v = vb * 4 + wave;
        if (v < VOCAB) {
            float er = emb[v * 64 + lane];       // lane = d
            float al = 0.f, ar = 0.f;
#pragma unroll 8
            for (int d = 0; d < 64; ++d) {
                float e = BCASTF(er, d);
                al += e * W1l[d * 64 + lane];
                ar += e * W1r[d * 64 + lane];
            }
            embW1l[v * 64 + lane] = al;
            embW1r[v * 64 + lane] = ar;
        }
        // W2 B-fragment packing: g = tt*1024 + h*512 + l*8 + j
        int g = vb * 256 + t;
        int j = g & 7, l = (g >> 3) & 63, h = (g >> 9) & 1, tt = g >> 10;
        int k = h * 32 + ((l >> 4) * 8) + j;
        int n = tt * 16 + (l & 15);
        float w = (n < 64) ? W2l[k * 64 + n] : W2r[k * 64 + (n - 64)];
        w2frag[g] = f2bf(w);
    }
}

// ---- per-bucket CSR build (rowstart/deg/col) + INLINE col16 fill --------
// col entry = src (17b) | x[src] (7b). col16[node][16]: first 16 neighbor
// indices (ZROW-padded), filled from slot-excl during the col write pass.
// Blocks 0..7 pack W1 B-fragments (needs scatter's embW1l -> later dispatch).
__global__ __launch_bounds__(256) void csr_kernel(
    const unsigned* __restrict__ edge8, const int* __restrict__ cursor,
    int* __restrict__ row_start, int* __restrict__ deg, int* __restrict__ col,
    int* __restrict__ col16,
    const float* __restrict__ embW1l, const float* __restrict__ embW1r,
    unsigned short* __restrict__ w1frag)
{
    __shared__ int cnt[CBUCKET];
    __shared__ int scn[CBUCKET];
    __shared__ int exs[CBUCKET];
    int b = blockIdx.x;                   // NBK blocks
    int t = threadIdx.x;

    // init this bucket's col16 region to ZROW (overwritten below for j<deg)
    for (int i = t * 4; i < CBUCKET * 16; i += 1024)
        *(int4*)&col16[b * CBUCKET * 16 + i] = (int4){ZROW, ZROW, ZROW, ZROW};

    if (b < 8) {
        // w1frag[( (kf*4+nt)*64 + l)*8 + j] = bf16 of B[k][n],
        //   k = kf*32 + (l>>4)*8 + j, n = nt*16 + (l&15); k>=128 -> embW1r
        int g0 = (b * 256 + t) * 8;
#pragma unroll
        for (int j = 0; j < 8; ++j) {
            int g = g0 + j;
            int fi = g >> 9;
            int kf = fi >> 2, nt = fi & 3;
            int l = (g >> 3) & 63, jj = g & 7;
            int kg = kf * 32 + ((l >> 4) << 3) + jj;
            int n = nt * 16 + (l & 15);
            float w = (kg < 128) ? embW1l[kg * 64 + n] : embW1r[(kg - 128) * 64 + n];
            w1frag[g] = f2bf(w);
        }
    }

    int lo = b * CAP, hi = lo + cursor[b];  // cursor holds final fill count
    cnt[t] = 0;
    __syncthreads();
    for (int i = lo + t; i < hi; i += 256)
        atomicAdd(&cnt[edge8[i] >> 24], 1);
    __syncthreads();
    int v = cnt[t];
    scn[t] = v;
    __syncthreads();
    for (int off = 1; off < 256; off <<= 1) {
        int tmp = (t >= off) ? scn[t - off] : 0;
        __syncthreads();
        scn[t] += tmp;
        __syncthreads();
    }
    int excl = scn[t] - v;
    int node = b * CBUCKET + t;
    if (node < N_NODES) { row_start[node] = lo + excl; deg[node] = v; }
    cnt[t] = excl;                        // reuse as cursor
    exs[t] = excl;                        // keep excl for local-slot calc
    __syncthreads();
    for (int i = lo + t; i < hi; i += 256) {
        unsigned e = edge8[i];
        int ld = (int)(e >> 24);
        int slot = atomicAdd(&cnt[ld], 1);
        col[lo + slot] = (int)(e & 0xFFFFFF);   // src | x<<17 (24 bits)
        int local = slot - exs[ld];
        if (local < 16)
            col16[(b * CBUCKET + ld) * 16 + local] = (int)(e & 0x1FFFF);
    }
}

// ---- sage1, histogram-MFMA form (round-4 proven, unchanged) -------------
__global__ __launch_bounds__(256) void sage1_kernel(
    const int* __restrict__ x, const int* __restrict__ deg,
    const unsigned* __restrict__ edge8, const int* __restrict__ cursor,
    const unsigned short* __restrict__ w1frag,
    const unsigned short* __restrict__ w2frag, const float* __restrict__ b1,
    unsigned char* __restrict__ p8, unsigned short* __restrict__ q16)
{
    __shared__ unsigned hist[128 * 32];         // 16 KB u8[128][128], swizzled words
    __shared__ unsigned short msbuf[128 * 72];  // 18 KB h1 bf16, stride 72
    __shared__ int xl[128];
    __shared__ float invd[128];

    int blk = blockIdx.x, bucket = blk >> 1, half = blk & 1;
    int t = threadIdx.x;
    int nbase = bucket * CBUCKET + half * 128;

    for (int i = t * 4; i < 128 * 32; i += 1024)
        *(uint4*)&hist[i] = (uint4){0u, 0u, 0u, 0u};
    if (t < 128) {
        int node = nbase + t;
        int dv = (node < N_NODES) ? deg[node] : 0;
        invd[t] = 1.0f / fmaxf((float)dv, 1.0f);
        xl[t] = (node < N_NODES) ? x[node] : 0;
    }
    __syncthreads();

    int lo = bucket * CAP, ecnt = cursor[bucket];
    for (int i = t; i < ecnt; i += 256) {
        unsigned e = edge8[lo + i];
        int ld = (int)(e >> 24);
        if ((ld >> 7) == half) {
            int r = ld & 127;
            int xv = (int)((e >> 17) & 127);
            int wc = (xv >> 2) ^ ((r & 7) << 2);        // word swizzle
            atomicAdd(&hist[r * 32 + wc], 1u << ((xv & 3) * 8));
        }
    }
    __syncthreads();

    int wave = t >> 6, lane = t & 63;
    int m = lane & 15;                  // A row / C col index
    int qd = lane >> 4;                 // k-subchunk / C row-group
    int hswz = (m & 7) << 2;            // row m's word swizzle

#pragma unroll
    for (int rt = wave * 2; rt < wave * 2 + 2; ++rt) {
        short8 acnt[4], aself[4];
#pragma unroll
        for (int kf = 0; kf < 4; ++kf) {
            int w0 = (kf * 8 + qd * 2) ^ hswz;
            uint2 u = *(const uint2*)&hist[(rt * 16 + m) * 32 + w0];
            short8 f;
            f[0] = (short)f2bf((float)(u.x & 255));
            f[1] = (short)f2bf((float)((u.x >> 8) & 255));
            f[2] = (short)f2bf((float)((u.x >> 16) & 255));
            f[3] = (short)f2bf((float)(u.x >> 24));
            f[4] = (short)f2bf((float)(u.y & 255));
            f[5] = (short)f2bf((float)((u.y >> 8) & 255));
            f[6] = (short)f2bf((float)((u.y >> 16) & 255));
            f[7] = (short)f2bf((float)(u.y >> 24));
            acnt[kf] = f;
        }
        int xv = xl[rt * 16 + m];
#pragma unroll
        for (int kf = 0; kf < 4; ++kf) {
            int v = xv - kf * 32 - qd * 8;
            short8 f;
#pragma unroll
            for (int j = 0; j < 8; ++j)
                f[j] = (v == j) ? (short)0x3F80 : (short)0;
            aself[kf] = f;
        }
        float iv0 = invd[rt * 16 + qd * 4 + 0];
        float iv1 = invd[rt * 16 + qd * 4 + 1];
        float iv2 = invd[rt * 16 + qd * 4 + 2];
        float iv3 = invd[rt * 16 + qd * 4 + 3];

#pragma unroll
        for (int nt = 0; nt < 4; ++nt) {
            f32x4 accA = {0.f, 0.f, 0.f, 0.f};
            f32x4 accS = {0.f, 0.f, 0.f, 0.f};
#pragma unroll
            for (int kf = 0; kf < 4; ++kf) {
                short8 bA = *(const short8*)(w1frag + ((kf * 4 + nt) * 64 + lane) * 8);
                accA = __builtin_amdgcn_mfma_f32_16x16x32_bf16(acnt[kf], bA, accA, 0, 0, 0);
            }
#pragma unroll
            for (int kf = 0; kf < 4; ++kf) {
                short8 bS = *(const short8*)(w1frag + (((kf + 4) * 4 + nt) * 64 + lane) * 8);
                accS = __builtin_amdgcn_mfma_f32_16x16x32_bf16(aself[kf], bS, accS, 0, 0, 0);
            }
            int c = nt * 16 + m;
            float b1c = b1[c];
            int rb = rt * 16 + qd * 4;
            msbuf[(rb + 0) * 72 + c] = f2bf(fmaxf(accA[0] * iv0 + accS[0] + b1c, 0.f));
            msbuf[(rb + 1) * 72 + c] = f2bf(fmaxf(accA[1] * iv1 + accS[1] + b1c, 0.f));
            msbuf[(rb + 2) * 72 + c] = f2bf(fmaxf(accA[2] * iv2 + accS[2] + b1c, 0.f));
            msbuf[(rb + 3) * 72 + c] = f2bf(fmaxf(accA[3] * iv3 + accS[3] + b1c, 0.f));
        }
    }
    __syncthreads();

#pragma unroll
    for (int rt = wave * 2; rt < wave * 2 + 2; ++rt) {
        const unsigned short* arow = &msbuf[(rt * 16 + m) * 72 + qd * 8];
        short8 a0 = *(const short8*)(arow);
        short8 a1 = *(const short8*)(arow + 32);
        int rowb = nbase + rt * 16 + qd * 4;

#pragma unroll
        for (int tt = 0; tt < 8; ++tt) {
            short8 b0 = *(const short8*)(w2frag + tt * 1024 + lane * 8);
            short8 b1v = *(const short8*)(w2frag + tt * 1024 + 512 + lane * 8);
            f32x4 acc = {0.f, 0.f, 0.f, 0.f};
            acc = __builtin_amdgcn_mfma_f32_16x16x32_bf16(a0, b0, acc, 0, 0, 0);
            acc = __builtin_amdgcn_mfma_f32_16x16x32_bf16(a1, b1v, acc, 0, 0, 0);
            int o = tt * 16 + m;
            if (o < 64) {
                int pk01 = __builtin_amdgcn_cvt_pk_fp8_f32(acc[0], acc[1], 0, false);
                int pk23 = __builtin_amdgcn_cvt_pk_fp8_f32(acc[2], acc[3], 0, false);
                if (rowb + 0 < N_NODES) p8[(rowb + 0) * 64 + o] = (unsigned char)(pk01 & 0xff);
                if (rowb + 1 < N_NODES) p8[(rowb + 1) * 64 + o] = (unsigned char)((pk01 >> 8) & 0xff);
                if (rowb + 2 < N_NODES) p8[(rowb + 2) * 64 + o] = (unsigned char)(pk23 & 0xff);
                if (rowb + 3 < N_NODES) p8[(rowb + 3) * 64 + o] = (unsigned char)((pk23 >> 8) & 0xff);
            } else {
                int oc = o & 63;
#pragma unroll
                for (int i = 0; i < 4; ++i)
                    if (rowb + i < N_NODES)
                        q16[(rowb + i) * 64 + oc] = f2bf(acc[i]);
            }
        }
    }
}

// ---- sage2: direct col16 addresses (no cross-lane ops in address path),
//   TWO-BATCH issue: per batch {16 idx loads | SB | 16 p-gathers + 4 q-rows
//   | SB | consume 2 pairs}. Peak live regs ~55 -> stays UNDER the 64-VGPR
//   occupancy cliff (round-6 lesson: 64 VGPR cost 56%->33% occupancy).
#define S2_NPW 8
__global__ __launch_bounds__(256) void sage2_kernel(
    const unsigned char* __restrict__ p, const unsigned short* __restrict__ q,
    const int* __restrict__ row_start, const int* __restrict__ deg,
    const int* __restrict__ col, const int* __restrict__ col16,
    const float* __restrict__ b2,
    const float* __restrict__ Wout, const int* __restrict__ batch,
    float* __restrict__ gsum)
{
    int t = threadIdx.x;
    int wave = t >> 6, lane = t & 63;
    int base_node = (blockIdx.x * 4 + wave) * S2_NPW;   // exact cover
    int c = lane & 15;          // feature quad: features 4c..4c+3
    int g = lane >> 4;          // row group 0..3

    float4 b2v = ((const float4*)b2)[c];
    float4 w01 = ((const float4*)Wout)[c * 2];
    float4 w23 = ((const float4*)Wout)[c * 2 + 1];

    int dgs[S2_NPW];
#pragma unroll
    for (int n = 0; n < S2_NPW; ++n)
        dgs[n] = deg[base_node + n];

#define ACC(a, v) { f32x2 f01_ = __builtin_amdgcn_cvt_pk_f32_fp8((int)(v), false); \
                    f32x2 f23_ = __builtin_amdgcn_cvt_pk_f32_fp8((int)(v), true);  \
                    (a).x += f01_.x; (a).y += f01_.y; (a).z += f23_.x; (a).w += f23_.y; }

#pragma unroll
    for (int hb = 0; hb < 2; ++hb) {
        int nb = hb * 4;                        // nodes base_node+nb .. +nb+3

        // ---- batch issue: 16 idx loads (rows g,4+g,8+g,12+g per node) ----
        int idx[4][4];
#pragma unroll
        for (int nn = 0; nn < 4; ++nn) {
            const int* cp = col16 + (size_t)(base_node + nb + nn) * 16 + g;
            idx[nn][0] = cp[0];
            idx[nn][1] = cp[4];
            idx[nn][2] = cp[8];
            idx[nn][3] = cp[12];
        }
        __builtin_amdgcn_sched_barrier(0);

        // ---- 16 p-gathers + 4 q-rows, all independent, in flight ----
        unsigned vv[4][4];
        ushort4 qv4[4];
#pragma unroll
        for (int nn = 0; nn < 4; ++nn) {
            vv[nn][0] = *(const unsigned*)(p + (size_t)idx[nn][0] * 64 + c * 4);
            vv[nn][1] = *(const unsigned*)(p + (size_t)idx[nn][1] * 64 + c * 4);
            vv[nn][2] = *(const unsigned*)(p + (size_t)idx[nn][2] * 64 + c * 4);
            vv[nn][3] = *(const unsigned*)(p + (size_t)idx[nn][3] * 64 + c * 4);
        }
#pragma unroll
        for (int nn = 0; nn < 4; ++nn)
            qv4[nn] = *(const ushort4*)(q + (size_t)(base_node + nb + nn) * 64 + c * 4);
        __builtin_amdgcn_sched_barrier(0);

        // ---- consume the two pairs of this batch ----
#pragma unroll
        for (int pp = 0; pp < 2; ++pp) {
            int la = pp * 2, lb = pp * 2 + 1;           // local in vv/qv4
            int na = nb + la, nbd = nb + lb;            // local in dgs
            int dgA = dgs[na], dgB = dgs[nbd];

            float4 aA = {0.f,0.f,0.f,0.f}, aB = {0.f,0.f,0.f,0.f};
            ACC(aA, vv[la][0]) ACC(aA, vv[la][1]) ACC(aA, vv[la][2]) ACC(aA, vv[la][3])
            ACC(aB, vv[lb][0]) ACC(aB, vv[lb][1]) ACC(aB, vv[lb][2]) ACC(aB, vv[lb][3])

            // --- deg>16 tail: direct col loads, guarded (rare, ~2.6%) ---
            if (dgA > 16) {
                int rsA = row_start[base_node + na];
                for (int j = 16; j < dgA; j += 8) {
                    int r0 = j + g, r1 = j + 4 + g;
                    int i0 = (r0 < dgA) ? (col[rsA + r0] & 0x1FFFF) : ZROW;
                    int i1 = (r1 < dgA) ? (col[rsA + r1] & 0x1FFFF) : ZROW;
                    unsigned v0 = *(const unsigned*)(p + (size_t)i0 * 64 + c * 4);
                    unsigned v1 = *(const unsigned*)(p + (size_t)i1 * 64 + c * 4);
                    ACC(aA, v0) ACC(aA, v1)
                }
            }
            if (dgB > 16) {
                int rsB = row_start[base_node + nbd];
                for (int j = 16; j < dgB; j += 8) {
                    int r0 = j + g, r1 = j + 4 + g;
                    int i0 = (r0 < dgB) ? (col[rsB + r0] & 0x1FFFF) : ZROW;
                    int i1 = (r1 < dgB) ? (col[rsB + r1] & 0x1FFFF) : ZROW;
                    unsigned v0 = *(const unsigned*)(p + (size_t)i0 * 64 + c * 4);
                    unsigned v1 = *(const unsigned*)(p + (size_t)i1 * 64 + c * 4);
                    ACC(aB, v0) ACC(aB, v1)
                }
            }

            // --- cross-group reduce ---
            aA.x += __shfl_xor(aA.x, 16, 64); aA.y += __shfl_xor(aA.y, 16, 64);
            aA.z += __shfl_xor(aA.z, 16, 64); aA.w += __shfl_xor(aA.w, 16, 64);
            aB.x += __shfl_xor(aB.x, 16, 64); aB.y += __shfl_xor(aB.y, 16, 64);
            aB.z += __shfl_xor(aB.z, 16, 64); aB.w += __shfl_xor(aB.w, 16, 64);
            aA.x += __shfl_xor(aA.x, 32, 64); aA.y += __shfl_xor(aA.y, 32, 64);
            aA.z += __shfl_xor(aA.z, 32, 64); aA.w += __shfl_xor(aA.w, 32, 64);
            aB.x += __shfl_xor(aB.x, 32, 64); aB.y += __shfl_xor(aB.y, 32, 64);
            aB.z += __shfl_xor(aB.z, 32, 64); aB.w += __shfl_xor(aB.w, 32, 64);

            // --- epilogue for both nodes ---
#pragma unroll
            for (int e = 0; e < 2; ++e) {
                int node = base_node + nb + pp * 2 + e;
                int dg = (e == 0) ? dgA : dgB;
                float4 a = (e == 0) ? aA : aB;
                ushort4 qvv = qv4[pp * 2 + e];
                float inv = 1.0f / fmaxf((float)dg, 1.0f);
                float h0 = fmaxf(a.x * inv + b2v.x + bf2f(qvv.x), 0.f);
                float h1 = fmaxf(a.y * inv + b2v.y + bf2f(qvv.y), 0.f);
                float h2 = fmaxf(a.z * inv + b2v.z + bf2f(qvv.z), 0.f);
                float h3 = fmaxf(a.w * inv + b2v.w + bf2f(qvv.w), 0.f);

                float p0 = h0 * w01.x + h1 * w01.z + h2 * w23.x + h3 * w23.z;
                float p1 = h0 * w01.y + h1 * w01.w + h2 * w23.y + h3 * w23.w;
                if (g != 0) { p0 = 0.f; p1 = 0.f; }     // groups duplicate
                p0 += __shfl_down(p0, 8, 64);  p1 += __shfl_down(p1, 8, 64);
                p0 += __shfl_down(p0, 4, 64);  p1 += __shfl_down(p1, 4, 64);
                p0 += __shfl_down(p0, 2, 64);  p1 += __shfl_down(p1, 2, 64);
                p0 += __shfl_down(p0, 1, 64);  p1 += __shfl_down(p1, 1, 64);
                if (lane == 0) {
                    int grp = batch[node];
                    atomicAdd(&gsum[grp * 2 + 0], p0);
                    atomicAdd(&gsum[grp * 2 + 1], p1);
                }
            }
        }
    }
#undef ACC
}

// ---------------- finalize: out = gsum/cnt + bout ----------------
__global__ __launch_bounds__(256) void finalize_kernel(
    const float* __restrict__ gsum, const int* __restrict__ gstart,
    const float* __restrict__ bout, float* __restrict__ out)
{
    int g = blockIdx.x * 256 + threadIdx.x;
    if (g >= N_GRAPHS) return;
    int cnt = gstart[g + 1] - gstart[g];
    float inv = 1.0f / fmaxf((float)cnt, 1.0f);
    out[g * 2 + 0] = gsum[g * 2 + 0] * inv + bout[0];
    out[g * 2 + 1] = gsum[g * 2 + 1] * inv + bout[1];
}

extern "C" void kernel_launch(void* const* d_in, const int* in_sizes, int n_in,
                              void* d_out, int out_size, void* d_ws, size_t ws_size,
                              hipStream_t stream) {
    const int*   x    = (const int*)  d_in[0];
    const int*   ei   = (const int*)  d_in[1];
    const int*   batch= (const int*)  d_in[2];
    const float* emb  = (const float*)d_in[3];
    const float* W1l  = (const float*)d_in[4];
    const float* b1   = (const float*)d_in[5];
    const float* W1r  = (const float*)d_in[6];
    const float* W2l  = (const float*)d_in[7];
    const float* b2   = (const float*)d_in[8];
    const float* W2r  = (const float*)d_in[9];
    const float* Wout = (const float*)d_in[10];
    const float* bout = (const float*)d_in[11];
    float* out = (float*)d_out;

    const int* src = ei;
    const int* dst = ei + N_EDGES;

    char* ws = (char*)d_ws;
    size_t off = 0;
    unsigned char*  p8     = (unsigned char*) (ws + off); off += (size_t)N_NODES * 64 + 64; // +64B zero row
    unsigned short* q16    = (unsigned short*)(ws + off); off += (size_t)N_NODES * 64 * 2;  // 12.8 MB
    unsigned short* w2frag = (unsigned short*)(ws + off); off += (size_t)8192 * 2;
    unsigned short* w1frag = (unsigned short*)(ws + off); off += (size_t)16384 * 2;         // 32 KB
    float*    embW1l = (float*)   (ws + off); off += (size_t)VOCAB * 64 * 4;
    float*    embW1r = (float*)   (ws + off); off += (size_t)VOCAB * 64 * 4;
    int*      rowst  = (int*)     (ws + off); off += (size_t)N_NODES * 4;
    int*      deg    = (int*)     (ws + off); off += (size_t)N_NODES * 4;
    int*      col    = (int*)     (ws + off); off += (size_t)(NBK * CAP + 256) * 4;   // 6.4 MB
    int*      col16  = (int*)     (ws + off); off += (size_t)NBK * CBUCKET * 16 * 4;  // 6.4 MB
    unsigned* edge8  = (unsigned*)(ws + off); off += (size_t)NBK * CAP * 4;           // 6.4 MB
    int*      gstart = (int*)     (ws + off); off += (size_t)(N_GRAPHS + 1) * 4;
    // contiguous zero region: cursor | gsum (one memset)
    int*      cursor = (int*)     (ws + off); off += (size_t)NBK * 4;
    float*    gsum   = (float*)   (ws + off); off += (size_t)N_GRAPHS * 2 * 4;

    hipMemsetAsync(cursor, 0, (size_t)NBK * 4 + (size_t)N_GRAPHS * 2 * 4, stream);

    scatter_kernel<<<SCAT_BLOCKS + GB + 32, 256, 0, stream>>>(
        src, dst, x, cursor, edge8,
        batch, gstart, emb, W1l, W1r, W2l, W2r, embW1l, embW1r, w2frag, p8);
    csr_kernel<<<NBK, 256, 0, stream>>>(edge8, cursor, rowst, deg, col, col16,
                                        embW1l, embW1r, w1frag);
    sage1_kernel<<<NBK * 2, 256, 0, stream>>>(
        x, deg, edge8, cursor, w1frag, w2frag, b1, p8, q16);
    sage2_kernel<<<N_NODES / (4 * S2_NPW), 256, 0, stream>>>(
        p8, q16, rowst, deg, col, col16, b2, Wout, batch, gsum);
    finalize_kernel<<<(N_GRAPHS + 255) / 256, 256, 0, stream>>>(gsum, gstart, bout, out);
}

// Round 9
// 196.070 us; speedup vs baseline: 1.1544x; 1.0191x over previous
//
#include <hip/hip_runtime.h>
#include <hip/hip_bf16.h>

#define N_NODES 100000
#define N_EDGES 1000000
#define EMB 64
#define HID 64
#define VOCAB 128
#define N_GRAPHS 2048

#define CBUCKET 256                                    // nodes per bucket
#define NBK ((N_NODES + CBUCKET - 1) / CBUCKET)        // 391
#define CAP 4096                                       // slots per bucket (E[cnt]=2560, 30 sigma)
#define CHUNK 4096
#define SCAT_BLOCKS ((N_EDGES + CHUNK - 1) / CHUNK)    // 245
#define GB ((N_NODES + 255) / 256)                     // 391 gstart blocks
#define ZROW N_NODES                                   // zero-row index in p8

#define BCASTF(v, l) __int_as_float(__builtin_amdgcn_readlane(__float_as_int(v), (l)))

typedef __attribute__((ext_vector_type(8))) short short8;
typedef __attribute__((ext_vector_type(4))) float f32x4;
typedef __attribute__((ext_vector_type(2))) float f32x2;

__device__ __forceinline__ float bf2f(unsigned short u) {
    return __uint_as_float((unsigned)u << 16);
}
__device__ __forceinline__ float bf2f_lo(unsigned u) {
    return __uint_as_float(u << 16);
}
__device__ __forceinline__ float bf2f_hi(unsigned u) {
    return __uint_as_float(u & 0xffff0000u);
}
__device__ __forceinline__ unsigned short f2bf(float f) {
    return __bfloat16_as_ushort(__float2bfloat16(f));
}

// ---- merged scatter + setup: blocks [0,245) scatter, [245,636) gstart,
//      [636,668) precompute. cursor/gsum pre-zeroed by one memset.
__global__ __launch_bounds__(256) void scatter_kernel(
    const int* __restrict__ src, const int* __restrict__ dst,
    const int* __restrict__ x,
    int* __restrict__ cursor, unsigned* __restrict__ edge8,
    const int* __restrict__ batch, int* __restrict__ gstart,
    const float* __restrict__ emb, const float* __restrict__ W1l,
    const float* __restrict__ W1r,
    const float* __restrict__ W2l, const float* __restrict__ W2r,
    float* __restrict__ embW1l, float* __restrict__ embW1r,
    unsigned short* __restrict__ w2frag, unsigned char* __restrict__ p8z)
{
    __shared__ unsigned earr[CHUNK];            // 16 KB packed payload
    __shared__ unsigned short karr[CHUNK];      // 8 KB bucket key (0..390)
    __shared__ int bcnt[NBK];
    __shared__ int bbase[NBK];
    int b = blockIdx.x;
    int t = threadIdx.x;

    if (b < SCAT_BLOCKS) {
        // ---- scatter: LDS-staged chunk, per-(block,bucket) run reservation
        // 32-bit payload: src(17) | x[src](7, bits 17..23) | local_dst(8, bits 24..31)
        for (int i = t; i < NBK; i += 256) bcnt[i] = 0;
        __syncthreads();
        int e0 = b * CHUNK;
        int n = min(e0 + CHUNK, N_EDGES) - e0;
        for (int i = t; i < n; i += 256) {
            int d = dst[e0 + i];
            int s = src[e0 + i];
            int xv = x[s];                      // random 4B read, 400KB L2-hot
            int k = d >> 8;
            earr[i] = (unsigned)s | ((unsigned)xv << 17) | ((unsigned)(d & 255) << 24);
            karr[i] = (unsigned short)k;
            atomicAdd(&bcnt[k], 1);
        }
        __syncthreads();
        for (int i = t; i < NBK; i += 256) {
            int c = bcnt[i];
            bbase[i] = i * CAP + (c ? atomicAdd(&cursor[i], c) : 0);
            bcnt[i] = 0;                        // reuse as local cursor
        }
        __syncthreads();
        for (int i = t; i < n; i += 256) {
            int k = karr[i];
            int off = atomicAdd(&bcnt[k], 1);
            edge8[bbase[k] + off] = earr[i];    // dense single-writer runs
        }
    } else if (b < SCAT_BLOCKS + GB) {
        // ---- graph boundaries (batch sorted)
        int i = (b - SCAT_BLOCKS) * 256 + t;
        if (i >= N_NODES) return;
        int bg = batch[i];
        int bp = (i == 0) ? -1 : batch[i - 1];
        for (int g = bp + 1; g <= bg; ++g) gstart[g] = i;
        if (i == N_NODES - 1)
            for (int g = bg + 1; g <= N_GRAPHS; ++g) gstart[g] = N_NODES;
    } else {
        // ---- precompute embW1l/embW1r + pack W2 B-fragments
        int vb = b - SCAT_BLOCKS - GB;
        // zero-row for sage2's branch-free gather (fp8 0x00 == +0.0)
        if (vb == 0 && t < 16)
            ((unsigned*)(p8z + (size_t)N_NODES * 64))[t] = 0u;
        int wave = t >> 6, lane = t & 63;
        int v = vb * 4 + wave;
        if (v < VOCAB) {
            float er = emb[v * 64 + lane];       // lane = d
            float al = 0.f, ar = 0.f;
#pragma unroll 8
            for (int d = 0; d < 64; ++d) {
                float e = BCASTF(er, d);
                al += e * W1l[d * 64 + lane];
                ar += e * W1r[d * 64 + lane];
            }
            embW1l[v * 64 + lane] = al;
            embW1r[v * 64 + lane] = ar;
        }
        // W2 B-fragment packing: g = tt*1024 + h*512 + l*8 + j
        int g = vb * 256 + t;
        int j = g & 7, l = (g >> 3) & 63, h = (g >> 9) & 1, tt = g >> 10;
        int k = h * 32 + ((l >> 4) * 8) + j;
        int n = tt * 16 + (l & 15);
        float w = (n < 64) ? W2l[k * 64 + n] : W2r[k * 64 + (n - 64)];
        w2frag[g] = f2bf(w);
    }
}

// ---- per-bucket CSR build (rowstart/deg/col) + INLINE col16 fill --------
__global__ __launch_bounds__(256) void csr_kernel(
    const unsigned* __restrict__ edge8, const int* __restrict__ cursor,
    int* __restrict__ row_start, int* __restrict__ deg, int* __restrict__ col,
    int* __restrict__ col16,
    const float* __restrict__ embW1l, const float* __restrict__ embW1r,
    unsigned short* __restrict__ w1frag)
{
    __shared__ int cnt[CBUCKET];
    __shared__ int scn[CBUCKET];
    __shared__ int exs[CBUCKET];
    int b = blockIdx.x;                   // NBK blocks
    int t = threadIdx.x;

    // init this bucket's col16 region to ZROW (overwritten below for j<deg)
    for (int i = t * 4; i < CBUCKET * 16; i += 1024)
        *(int4*)&col16[b * CBUCKET * 16 + i] = (int4){ZROW, ZROW, ZROW, ZROW};

    if (b < 8) {
        // w1frag[( (kf*4+nt)*64 + l)*8 + j] = bf16 of B[k][n],
        //   k = kf*32 + (l>>4)*8 + j, n = nt*16 + (l&15); k>=128 -> embW1r
        int g0 = (b * 256 + t) * 8;
#pragma unroll
        for (int j = 0; j < 8; ++j) {
            int g = g0 + j;
            int fi = g >> 9;
            int kf = fi >> 2, nt = fi & 3;
            int l = (g >> 3) & 63, jj = g & 7;
            int kg = kf * 32 + ((l >> 4) << 3) + jj;
            int n = nt * 16 + (l & 15);
            float w = (kg < 128) ? embW1l[kg * 64 + n] : embW1r[(kg - 128) * 64 + n];
            w1frag[g] = f2bf(w);
        }
    }

    int lo = b * CAP, hi = lo + cursor[b];  // cursor holds final fill count
    cnt[t] = 0;
    __syncthreads();
    for (int i = lo + t; i < hi; i += 256)
        atomicAdd(&cnt[edge8[i] >> 24], 1);
    __syncthreads();
    int v = cnt[t];
    scn[t] = v;
    __syncthreads();
    for (int off = 1; off < 256; off <<= 1) {
        int tmp = (t >= off) ? scn[t - off] : 0;
        __syncthreads();
        scn[t] += tmp;
        __syncthreads();
    }
    int excl = scn[t] - v;
    int node = b * CBUCKET + t;
    if (node < N_NODES) { row_start[node] = lo + excl; deg[node] = v; }
    cnt[t] = excl;                        // reuse as cursor
    exs[t] = excl;                        // keep excl for local-slot calc
    __syncthreads();
    for (int i = lo + t; i < hi; i += 256) {
        unsigned e = edge8[i];
        int ld = (int)(e >> 24);
        int slot = atomicAdd(&cnt[ld], 1);
        col[lo + slot] = (int)(e & 0xFFFFFF);   // src | x<<17 (24 bits)
        int local = slot - exs[ld];
        if (local < 16)
            col16[(b * CBUCKET + ld) * 16 + local] = (int)(e & 0x1FFFF);
    }
}

// ---- sage1, histogram-MFMA form (round-4 proven, unchanged) -------------
__global__ __launch_bounds__(256) void sage1_kernel(
    const int* __restrict__ x, const int* __restrict__ deg,
    const unsigned* __restrict__ edge8, const int* __restrict__ cursor,
    const unsigned short* __restrict__ w1frag,
    const unsigned short* __restrict__ w2frag, const float* __restrict__ b1,
    unsigned char* __restrict__ p8, unsigned short* __restrict__ q16)
{
    __shared__ unsigned hist[128 * 32];         // 16 KB u8[128][128], swizzled words
    __shared__ unsigned short msbuf[128 * 72];  // 18 KB h1 bf16, stride 72
    __shared__ int xl[128];
    __shared__ float invd[128];

    int blk = blockIdx.x, bucket = blk >> 1, half = blk & 1;
    int t = threadIdx.x;
    int nbase = bucket * CBUCKET + half * 128;

    for (int i = t * 4; i < 128 * 32; i += 1024)
        *(uint4*)&hist[i] = (uint4){0u, 0u, 0u, 0u};
    if (t < 128) {
        int node = nbase + t;
        int dv = (node < N_NODES) ? deg[node] : 0;
        invd[t] = 1.0f / fmaxf((float)dv, 1.0f);
        xl[t] = (node < N_NODES) ? x[node] : 0;
    }
    __syncthreads();

    int lo = bucket * CAP, ecnt = cursor[bucket];
    for (int i = t; i < ecnt; i += 256) {
        unsigned e = edge8[lo + i];
        int ld = (int)(e >> 24);
        if ((ld >> 7) == half) {
            int r = ld & 127;
            int xv = (int)((e >> 17) & 127);
            int wc = (xv >> 2) ^ ((r & 7) << 2);        // word swizzle
            atomicAdd(&hist[r * 32 + wc], 1u << ((xv & 3) * 8));
        }
    }
    __syncthreads();

    int wave = t >> 6, lane = t & 63;
    int m = lane & 15;                  // A row / C col index
    int qd = lane >> 4;                 // k-subchunk / C row-group
    int hswz = (m & 7) << 2;            // row m's word swizzle

#pragma unroll
    for (int rt = wave * 2; rt < wave * 2 + 2; ++rt) {
        short8 acnt[4], aself[4];
#pragma unroll
        for (int kf = 0; kf < 4; ++kf) {
            int w0 = (kf * 8 + qd * 2) ^ hswz;
            uint2 u = *(const uint2*)&hist[(rt * 16 + m) * 32 + w0];
            short8 f;
            f[0] = (short)f2bf((float)(u.x & 255));
            f[1] = (short)f2bf((float)((u.x >> 8) & 255));
            f[2] = (short)f2bf((float)((u.x >> 16) & 255));
            f[3] = (short)f2bf((float)(u.x >> 24));
            f[4] = (short)f2bf((float)(u.y & 255));
            f[5] = (short)f2bf((float)((u.y >> 8) & 255));
            f[6] = (short)f2bf((float)((u.y >> 16) & 255));
            f[7] = (short)f2bf((float)(u.y >> 24));
            acnt[kf] = f;
        }
        int xv = xl[rt * 16 + m];
#pragma unroll
        for (int kf = 0; kf < 4; ++kf) {
            int v = xv - kf * 32 - qd * 8;
            short8 f;
#pragma unroll
            for (int j = 0; j < 8; ++j)
                f[j] = (v == j) ? (short)0x3F80 : (short)0;
            aself[kf] = f;
        }
        float iv0 = invd[rt * 16 + qd * 4 + 0];
        float iv1 = invd[rt * 16 + qd * 4 + 1];
        float iv2 = invd[rt * 16 + qd * 4 + 2];
        float iv3 = invd[rt * 16 + qd * 4 + 3];

#pragma unroll
        for (int nt = 0; nt < 4; ++nt) {
            f32x4 accA = {0.f, 0.f, 0.f, 0.f};
            f32x4 accS = {0.f, 0.f, 0.f, 0.f};
#pragma unroll
            for (int kf = 0; kf < 4; ++kf) {
                short8 bA = *(const short8*)(w1frag + ((kf * 4 + nt) * 64 + lane) * 8);
                accA = __builtin_amdgcn_mfma_f32_16x16x32_bf16(acnt[kf], bA, accA, 0, 0, 0);
            }
#pragma unroll
            for (int kf = 0; kf < 4; ++kf) {
                short8 bS = *(const short8*)(w1frag + (((kf + 4) * 4 + nt) * 64 + lane) * 8);
                accS = __builtin_amdgcn_mfma_f32_16x16x32_bf16(aself[kf], bS, accS, 0, 0, 0);
            }
            int c = nt * 16 + m;
            float b1c = b1[c];
            int rb = rt * 16 + qd * 4;
            msbuf[(rb + 0) * 72 + c] = f2bf(fmaxf(accA[0] * iv0 + accS[0] + b1c, 0.f));
            msbuf[(rb + 1) * 72 + c] = f2bf(fmaxf(accA[1] * iv1 + accS[1] + b1c, 0.f));
            msbuf[(rb + 2) * 72 + c] = f2bf(fmaxf(accA[2] * iv2 + accS[2] + b1c, 0.f));
            msbuf[(rb + 3) * 72 + c] = f2bf(fmaxf(accA[3] * iv3 + accS[3] + b1c, 0.f));
        }
    }
    __syncthreads();

#pragma unroll
    for (int rt = wave * 2; rt < wave * 2 + 2; ++rt) {
        const unsigned short* arow = &msbuf[(rt * 16 + m) * 72 + qd * 8];
        short8 a0 = *(const short8*)(arow);
        short8 a1 = *(const short8*)(arow + 32);
        int rowb = nbase + rt * 16 + qd * 4;

#pragma unroll
        for (int tt = 0; tt < 8; ++tt) {
            short8 b0 = *(const short8*)(w2frag + tt * 1024 + lane * 8);
            short8 b1v = *(const short8*)(w2frag + tt * 1024 + 512 + lane * 8);
            f32x4 acc = {0.f, 0.f, 0.f, 0.f};
            acc = __builtin_amdgcn_mfma_f32_16x16x32_bf16(a0, b0, acc, 0, 0, 0);
            acc = __builtin_amdgcn_mfma_f32_16x16x32_bf16(a1, b1v, acc, 0, 0, 0);
            int o = tt * 16 + m;
            if (o < 64) {
                int pk01 = __builtin_amdgcn_cvt_pk_fp8_f32(acc[0], acc[1], 0, false);
                int pk23 = __builtin_amdgcn_cvt_pk_fp8_f32(acc[2], acc[3], 0, false);
                if (rowb + 0 < N_NODES) p8[(rowb + 0) * 64 + o] = (unsigned char)(pk01 & 0xff);
                if (rowb + 1 < N_NODES) p8[(rowb + 1) * 64 + o] = (unsigned char)((pk01 >> 8) & 0xff);
                if (rowb + 2 < N_NODES) p8[(rowb + 2) * 64 + o] = (unsigned char)(pk23 & 0xff);
                if (rowb + 3 < N_NODES) p8[(rowb + 3) * 64 + o] = (unsigned char)((pk23 >> 8) & 0xff);
            } else {
                int oc = o & 63;
#pragma unroll
                for (int i = 0; i < 4; ++i)
                    if (rowb + i < N_NODES)
                        q16[(rowb + i) * 64 + oc] = f2bf(acc[i]);
            }
        }
    }
}

// ---- sage2: inline-asm batched gather (round-8 design, hardened asm).
//   Per 4-node batch: asm block 1 = 16 idx loads (one voffset + offset: imm)
//   + single waitcnt; asm block 2 = 16 p-gathers + 8 q-dwords + single
//   waitcnt. HW keeps 16-24 loads in flight per wall; compiler cannot
//   reorder or drain early (loads and waitcnt share one asm volatile block).
#define S2_NPW 8
__global__ __launch_bounds__(256) void sage2_kernel(
    const unsigned char* __restrict__ p, const unsigned short* __restrict__ q,
    const int* __restrict__ row_start, const int* __restrict__ deg,
    const int* __restrict__ col, const int* __restrict__ col16,
    const float* __restrict__ b2,
    const float* __restrict__ Wout, const int* __restrict__ batch,
    float* __restrict__ gsum)
{
    int t = threadIdx.x;
    int wave = t >> 6, lane = t & 63;
    int base_node = (blockIdx.x * 4 + wave) * S2_NPW;   // exact cover
    int c = lane & 15;          // feature quad: features 4c..4c+3
    int g = lane >> 4;          // row group 0..3

    float4 b2v = ((const float4*)b2)[c];
    float4 w01 = ((const float4*)Wout)[c * 2];
    float4 w23 = ((const float4*)Wout)[c * 2 + 1];

    int dgs[S2_NPW];
#pragma unroll
    for (int n = 0; n < S2_NPW; ++n)
        dgs[n] = deg[base_node + n];

#define ACC(a, v) { f32x2 f01_ = __builtin_amdgcn_cvt_pk_f32_fp8((int)(v), false); \
                    f32x2 f23_ = __builtin_amdgcn_cvt_pk_f32_fp8((int)(v), true);  \
                    (a).x += f01_.x; (a).y += f01_.y; (a).z += f23_.x; (a).w += f23_.y; }

#pragma unroll
    for (int hb = 0; hb < 2; ++hb) {
        int nb = hb * 4;                        // nodes base_node+nb .. +nb+3

        // ---- asm block 1: 16 idx loads, one voffset, offset:nn*64+k*16 ----
        unsigned vc = (unsigned)((base_node + nb) * 64 + g * 4);
        unsigned i00, i01, i02, i03, i10, i11, i12, i13;
        unsigned i20, i21, i22, i23, i30, i31, i32, i33;
        asm volatile(
            "global_load_dword %0,  %16, %17\n\t"
            "global_load_dword %1,  %16, %17 offset:16\n\t"
            "global_load_dword %2,  %16, %17 offset:32\n\t"
            "global_load_dword %3,  %16, %17 offset:48\n\t"
            "global_load_dword %4,  %16, %17 offset:64\n\t"
            "global_load_dword %5,  %16, %17 offset:80\n\t"
            "global_load_dword %6,  %16, %17 offset:96\n\t"
            "global_load_dword %7,  %16, %17 offset:112\n\t"
            "global_load_dword %8,  %16, %17 offset:128\n\t"
            "global_load_dword %9,  %16, %17 offset:144\n\t"
            "global_load_dword %10, %16, %17 offset:160\n\t"
            "global_load_dword %11, %16, %17 offset:176\n\t"
            "global_load_dword %12, %16, %17 offset:192\n\t"
            "global_load_dword %13, %16, %17 offset:208\n\t"
            "global_load_dword %14, %16, %17 offset:224\n\t"
            "global_load_dword %15, %16, %17 offset:240\n\t"
            "s_waitcnt vmcnt(0)"
            : "=&v"(i00), "=&v"(i01), "=&v"(i02), "=&v"(i03),
              "=&v"(i10), "=&v"(i11), "=&v"(i12), "=&v"(i13),
              "=&v"(i20), "=&v"(i21), "=&v"(i22), "=&v"(i23),
              "=&v"(i30), "=&v"(i31), "=&v"(i32), "=&v"(i33)
            : "v"(vc), "s"(col16)
            : "memory");

        // ---- gather byte offsets: idx*64 + c*4 ----
        unsigned cc4 = (unsigned)(c << 2);
        unsigned o00 = (i00 << 6) + cc4, o01 = (i01 << 6) + cc4;
        unsigned o02 = (i02 << 6) + cc4, o03 = (i03 << 6) + cc4;
        unsigned o10 = (i10 << 6) + cc4, o11 = (i11 << 6) + cc4;
        unsigned o12 = (i12 << 6) + cc4, o13 = (i13 << 6) + cc4;
        unsigned o20 = (i20 << 6) + cc4, o21 = (i21 << 6) + cc4;
        unsigned o22 = (i22 << 6) + cc4, o23 = (i23 << 6) + cc4;
        unsigned o30 = (i30 << 6) + cc4, o31 = (i31 << 6) + cc4;
        unsigned o32 = (i32 << 6) + cc4, o33 = (i33 << 6) + cc4;
        unsigned vq = (unsigned)((base_node + nb) * 128 + c * 8);

        // ---- asm block 2: 16 p-gathers + 8 q-dwords, one waitcnt ----
        unsigned v00, v01, v02, v03, v10, v11, v12, v13;
        unsigned v20, v21, v22, v23, v30, v31, v32, v33;
        unsigned qa0, qb0, qa1, qb1, qa2, qb2, qa3, qb3;
        asm volatile(
            "global_load_dword %0,  %24, %41\n\t"
            "global_load_dword %1,  %25, %41\n\t"
            "global_load_dword %2,  %26, %41\n\t"
            "global_load_dword %3,  %27, %41\n\t"
            "global_load_dword %4,  %28, %41\n\t"
            "global_load_dword %5,  %29, %41\n\t"
            "global_load_dword %6,  %30, %41\n\t"
            "global_load_dword %7,  %31, %41\n\t"
            "global_load_dword %8,  %32, %41\n\t"
            "global_load_dword %9,  %33, %41\n\t"
            "global_load_dword %10, %34, %41\n\t"
            "global_load_dword %11, %35, %41\n\t"
            "global_load_dword %12, %36, %41\n\t"
            "global_load_dword %13, %37, %41\n\t"
            "global_load_dword %14, %38, %41\n\t"
            "global_load_dword %15, %39, %41\n\t"
            "global_load_dword %16, %40, %42\n\t"
            "global_load_dword %17, %40, %42 offset:4\n\t"
            "global_load_dword %18, %40, %42 offset:128\n\t"
            "global_load_dword %19, %40, %42 offset:132\n\t"
            "global_load_dword %20, %40, %42 offset:256\n\t"
            "global_load_dword %21, %40, %42 offset:260\n\t"
            "global_load_dword %22, %40, %42 offset:384\n\t"
            "global_load_dword %23, %40, %42 offset:388\n\t"
            "s_waitcnt vmcnt(0)"
            : "=&v"(v00), "=&v"(v01), "=&v"(v02), "=&v"(v03),
              "=&v"(v10), "=&v"(v11), "=&v"(v12), "=&v"(v13),
              "=&v"(v20), "=&v"(v21), "=&v"(v22), "=&v"(v23),
              "=&v"(v30), "=&v"(v31), "=&v"(v32), "=&v"(v33),
              "=&v"(qa0), "=&v"(qb0), "=&v"(qa1), "=&v"(qb1),
              "=&v"(qa2), "=&v"(qb2), "=&v"(qa3), "=&v"(qb3)
            : "v"(o00), "v"(o01), "v"(o02), "v"(o03),
              "v"(o10), "v"(o11), "v"(o12), "v"(o13),
              "v"(o20), "v"(o21), "v"(o22), "v"(o23),
              "v"(o30), "v"(o31), "v"(o32), "v"(o33),
              "v"(vq), "s"(p), "s"(q)
            : "memory");

        // ---- consume the two pairs of this batch ----
#pragma unroll
        for (int pp = 0; pp < 2; ++pp) {
            int na = nb + pp * 2, nbd = nb + pp * 2 + 1;
            int dgA = dgs[na], dgB = dgs[nbd];

            float4 aA = {0.f,0.f,0.f,0.f}, aB = {0.f,0.f,0.f,0.f};
            if (pp == 0) {
                ACC(aA, v00) ACC(aA, v01) ACC(aA, v02) ACC(aA, v03)
                ACC(aB, v10) ACC(aB, v11) ACC(aB, v12) ACC(aB, v13)
            } else {
                ACC(aA, v20) ACC(aA, v21) ACC(aA, v22) ACC(aA, v23)
                ACC(aB, v30) ACC(aB, v31) ACC(aB, v32) ACC(aB, v33)
            }

            // --- deg>16 tail: direct col loads, guarded (rare, ~2.6%) ---
            if (dgA > 16) {
                int rsA = row_start[base_node + na];
                for (int j = 16; j < dgA; j += 8) {
                    int r0 = j + g, r1 = j + 4 + g;
                    int i0 = (r0 < dgA) ? (col[rsA + r0] & 0x1FFFF) : ZROW;
                    int i1 = (r1 < dgA) ? (col[rsA + r1] & 0x1FFFF) : ZROW;
                    unsigned u0 = *(const unsigned*)(p + (size_t)i0 * 64 + c * 4);
                    unsigned u1 = *(const unsigned*)(p + (size_t)i1 * 64 + c * 4);
                    ACC(aA, u0) ACC(aA, u1)
                }
            }
            if (dgB > 16) {
                int rsB = row_start[base_node + nbd];
                for (int j = 16; j < dgB; j += 8) {
                    int r0 = j + g, r1 = j + 4 + g;
                    int i0 = (r0 < dgB) ? (col[rsB + r0] & 0x1FFFF) : ZROW;
                    int i1 = (r1 < dgB) ? (col[rsB + r1] & 0x1FFFF) : ZROW;
                    unsigned u0 = *(const unsigned*)(p + (size_t)i0 * 64 + c * 4);
                    unsigned u1 = *(const unsigned*)(p + (size_t)i1 * 64 + c * 4);
                    ACC(aB, u0) ACC(aB, u1)
                }
            }

            // --- cross-group reduce ---
            aA.x += __shfl_xor(aA.x, 16, 64); aA.y += __shfl_xor(aA.y, 16, 64);
            aA.z += __shfl_xor(aA.z, 16, 64); aA.w += __shfl_xor(aA.w, 16, 64);
            aB.x += __shfl_xor(aB.x, 16, 64); aB.y += __shfl_xor(aB.y, 16, 64);
            aB.z += __shfl_xor(aB.z, 16, 64); aB.w += __shfl_xor(aB.w, 16, 64);
            aA.x += __shfl_xor(aA.x, 32, 64); aA.y += __shfl_xor(aA.y, 32, 64);
            aA.z += __shfl_xor(aA.z, 32, 64); aA.w += __shfl_xor(aA.w, 32, 64);
            aB.x += __shfl_xor(aB.x, 32, 64); aB.y += __shfl_xor(aB.y, 32, 64);
            aB.z += __shfl_xor(aB.z, 32, 64); aB.w += __shfl_xor(aB.w, 32, 64);

            // --- epilogue for both nodes ---
#pragma unroll
            for (int e = 0; e < 2; ++e) {
                int node = base_node + nb + pp * 2 + e;
                int dg = (e == 0) ? dgA : dgB;
                float4 a = (e == 0) ? aA : aB;
                int li = pp * 2 + e;
                unsigned qlo = (li == 0) ? qa0 : (li == 1) ? qa1 : (li == 2) ? qa2 : qa3;
                unsigned qhi = (li == 0) ? qb0 : (li == 1) ? qb1 : (li == 2) ? qb2 : qb3;
                float inv = 1.0f / fmaxf((float)dg, 1.0f);
                float h0 = fmaxf(a.x * inv + b2v.x + bf2f_lo(qlo), 0.f);
                float h1 = fmaxf(a.y * inv + b2v.y + bf2f_hi(qlo), 0.f);
                float h2 = fmaxf(a.z * inv + b2v.z + bf2f_lo(qhi), 0.f);
                float h3 = fmaxf(a.w * inv + b2v.w + bf2f_hi(qhi), 0.f);

                float p0 = h0 * w01.x + h1 * w01.z + h2 * w23.x + h3 * w23.z;
                float p1 = h0 * w01.y + h1 * w01.w + h2 * w23.y + h3 * w23.w;
                if (g != 0) { p0 = 0.f; p1 = 0.f; }     // groups duplicate
                p0 += __shfl_down(p0, 8, 64);  p1 += __shfl_down(p1, 8, 64);
                p0 += __shfl_down(p0, 4, 64);  p1 += __shfl_down(p1, 4, 64);
                p0 += __shfl_down(p0, 2, 64);  p1 += __shfl_down(p1, 2, 64);
                p0 += __shfl_down(p0, 1, 64);  p1 += __shfl_down(p1, 1, 64);
                if (lane == 0) {
                    int grp = batch[node];
                    atomicAdd(&gsum[grp * 2 + 0], p0);
                    atomicAdd(&gsum[grp * 2 + 1], p1);
                }
            }
        }
    }
#undef ACC
}

// ---------------- finalize: out = gsum/cnt + bout ----------------
__global__ __launch_bounds__(256) void finalize_kernel(
    const float* __restrict__ gsum, const int* __restrict__ gstart,
    const float* __restrict__ bout, float* __restrict__ out)
{
    int g = blockIdx.x * 256 + threadIdx.x;
    if (g >= N_GRAPHS) return;
    int cnt = gstart[g + 1] - gstart[g];
    float inv = 1.0f / fmaxf((float)cnt, 1.0f);
    out[g * 2 + 0] = gsum[g * 2 + 0] * inv + bout[0];
    out[g * 2 + 1] = gsum[g * 2 + 1] * inv + bout[1];
}

extern "C" void kernel_launch(void* const* d_in, const int* in_sizes, int n_in,
                              void* d_out, int out_size, void* d_ws, size_t ws_size,
                              hipStream_t stream) {
    const int*   x    = (const int*)  d_in[0];
    const int*   ei   = (const int*)  d_in[1];
    const int*   batch= (const int*)  d_in[2];
    const float* emb  = (const float*)d_in[3];
    const float* W1l  = (const float*)d_in[4];
    const float* b1   = (const float*)d_in[5];
    const float* W1r  = (const float*)d_in[6];
    const float* W2l  = (const float*)d_in[7];
    const float* b2   = (const float*)d_in[8];
    const float* W2r  = (const float*)d_in[9];
    const float* Wout = (const float*)d_in[10];
    const float* bout = (const float*)d_in[11];
    float* out = (float*)d_out;

    const int* src = ei;
    const int* dst = ei + N_EDGES;

    char* ws = (char*)d_ws;
    size_t off = 0;
    unsigned char*  p8     = (unsigned char*) (ws + off); off += (size_t)N_NODES * 64 + 64; // +64B zero row
    unsigned short* q16    = (unsigned short*)(ws + off); off += (size_t)N_NODES * 64 * 2;  // 12.8 MB
    unsigned short* w2frag = (unsigned short*)(ws + off); off += (size_t)8192 * 2;
    unsigned short* w1frag = (unsigned short*)(ws + off); off += (size_t)16384 * 2;         // 32 KB
    float*    embW1l = (float*)   (ws + off); off += (size_t)VOCAB * 64 * 4;
    float*    embW1r = (float*)   (ws + off); off += (size_t)VOCAB * 64 * 4;
    int*      rowst  = (int*)     (ws + off); off += (size_t)N_NODES * 4;
    int*      deg    = (int*)     (ws + off); off += (size_t)N_NODES * 4;
    int*      col    = (int*)     (ws + off); off += (size_t)(NBK * CAP + 256) * 4;   // 6.4 MB
    int*      col16  = (int*)     (ws + off); off += (size_t)NBK * CBUCKET * 16 * 4;  // 6.4 MB
    unsigned* edge8  = (unsigned*)(ws + off); off += (size_t)NBK * CAP * 4;           // 6.4 MB
    int*      gstart = (int*)     (ws + off); off += (size_t)(N_GRAPHS + 1) * 4;
    // contiguous zero region: cursor | gsum (one memset)
    int*      cursor = (int*)     (ws + off); off += (size_t)NBK * 4;
    float*    gsum   = (float*)   (ws + off); off += (size_t)N_GRAPHS * 2 * 4;

    hipMemsetAsync(cursor, 0, (size_t)NBK * 4 + (size_t)N_GRAPHS * 2 * 4, stream);

    scatter_kernel<<<SCAT_BLOCKS + GB + 32, 256, 0, stream>>>(
        src, dst, x, cursor, edge8,
        batch, gstart, emb, W1l, W1r, W2l, W2r, embW1l, embW1r, w2frag, p8);
    csr_kernel<<<NBK, 256, 0, stream>>>(edge8, cursor, rowst, deg, col, col16,
                                        embW1l, embW1r, w1frag);
    sage1_kernel<<<NBK * 2, 256, 0, stream>>>(
        x, deg, edge8, cursor, w1frag, w2frag, b1, p8, q16);
    sage2_kernel<<<N_NODES / (4 * S2_NPW), 256, 0, stream>>>(
        p8, q16, rowst, deg, col, col16, b2, Wout, batch, gsum);
    finalize_kernel<<<(N_GRAPHS + 255) / 256, 256, 0, stream>>>(gsum, gstart, bout, out);
}